// Round 1
// baseline (87.055 us; speedup 1.0000x reference)
//
#include <hip/hip_runtime.h>

// ConjunctionLayer: out[b,j] = -1 / (-1 + sum_i log(1 - (1-x[b,i]) * W[j,i]))
// B=4096, INPUT_DIM=512, N=128, fp32.
//
// Mapping: lane <-> b (64 b per wave). Block = 4 waves = 64 b x 16 j, each
// wave owns 4 j across the full K=512 (accumulators in VGPRs, no reduction).
// W rows for the block (16x512 fp32 = 32 KB contiguous) staged in LDS once;
// inner-loop W reads are wave-uniform -> LDS broadcast (conflict-free).
// x tile (16 i) lives in registers, reused across the 4 j.
// Trick: sum of logs -> log of product-of-16 (z in (0.5,1] so p >= 0.5^16,
// safely normal fp32) -> 16x fewer v_log_f32. float2 ext-vectors encourage
// v_pk_fma_f32 / v_pk_mul_f32 packed math.

typedef float v2f __attribute__((ext_vector_type(2)));

constexpr int IDIM    = 512;
constexpr int NOUT    = 128;
constexpr int BTOT    = 4096;
constexpr int JT      = 16;            // j per block
constexpr int JW      = 4;             // j per wave
constexpr int BGROUPS = BTOT / 64;     // 64
constexpr int JGROUPS = NOUT / JT;     // 8
constexpr float LN2   = 0.69314718055994530942f;

__device__ __forceinline__ v2f mk2(float a, float b) {
    v2f r; r.x = a; r.y = b; return r;
}

__global__ __launch_bounds__(256, 2)
void conj_kernel(const float* __restrict__ x,
                 const float* __restrict__ W,
                 float* __restrict__ out)
{
    __shared__ float s_w[JT * IDIM];        // 32 KB: W rows j0..j0+15
    __shared__ float s_acc[64][JT + 1];     // padded transpose tile, 4.25 KB

    const int tid = threadIdx.x;
    // bg = blockIdx % 64 so the 8 j-sibling blocks (same x slice) land on the
    // same XCD under the idx%8 round-robin mapping -> x served from that L2.
    const int bg = blockIdx.x & (BGROUPS - 1);
    const int jg = blockIdx.x >> 6;
    const int j0 = jg * JT;
    const int b0 = bg * 64;

    // Stage W[j0 .. j0+16) -- contiguous 32 KB, coalesced float4 copy.
    {
        const float4* src = (const float4*)(W + (size_t)j0 * IDIM);
        float4* dst = (float4*)s_w;
        #pragma unroll
        for (int k = 0; k < (JT * IDIM / 4) / 256; ++k)   // 8 iters
            dst[tid + k * 256] = src[tid + k * 256];
    }
    __syncthreads();

    const int wave = tid >> 6;
    const int lane = tid & 63;
    const int b    = b0 + lane;
    const int jl0  = wave * JW;

    float acc[JW];
    #pragma unroll
    for (int jj = 0; jj < JW; ++jj) acc[jj] = 0.0f;

    const float4* xrow = (const float4*)(x + (size_t)b * IDIM);

    for (int t = 0; t < IDIM / 16; ++t) {
        // x[b][16t .. 16t+16) -> registers (one 64B line per lane)
        float4 x0 = xrow[t * 4 + 0];
        float4 x1 = xrow[t * 4 + 1];
        float4 x2 = xrow[t * 4 + 2];
        float4 x3 = xrow[t * 4 + 3];
        v2f xm[8];
        xm[0] = mk2(x0.x, x0.y) - 1.0f;
        xm[1] = mk2(x0.z, x0.w) - 1.0f;
        xm[2] = mk2(x1.x, x1.y) - 1.0f;
        xm[3] = mk2(x1.z, x1.w) - 1.0f;
        xm[4] = mk2(x2.x, x2.y) - 1.0f;
        xm[5] = mk2(x2.z, x2.w) - 1.0f;
        xm[6] = mk2(x3.x, x3.y) - 1.0f;
        xm[7] = mk2(x3.z, x3.w) - 1.0f;

        #pragma unroll
        for (int jj = 0; jj < JW; ++jj) {
            // wave-uniform address -> LDS broadcast reads
            const float4* wp = (const float4*)&s_w[(jl0 + jj) * IDIM + t * 16];
            float4 w0 = wp[0], w1 = wp[1], w2 = wp[2], w3 = wp[3];

            // z = 1 + (x-1)*w  (fp-contract -> v_pk_fma_f32)
            v2f z0 = xm[0] * mk2(w0.x, w0.y) + 1.0f;
            v2f z1 = xm[1] * mk2(w0.z, w0.w) + 1.0f;
            v2f z2 = xm[2] * mk2(w1.x, w1.y) + 1.0f;
            v2f z3 = xm[3] * mk2(w1.z, w1.w) + 1.0f;
            v2f z4 = xm[4] * mk2(w2.x, w2.y) + 1.0f;
            v2f z5 = xm[5] * mk2(w2.z, w2.w) + 1.0f;
            v2f z6 = xm[6] * mk2(w3.x, w3.y) + 1.0f;
            v2f z7 = xm[7] * mk2(w3.z, w3.w) + 1.0f;

            // product tree of 16 z's -> one log
            v2f p0 = z0 * z1, p1 = z2 * z3, p2 = z4 * z5, p3 = z6 * z7;
            v2f q0 = p0 * p1, q1 = p2 * p3;
            v2f q  = q0 * q1;
            float p = q.x * q.y;                 // p in (0.5^16, 1]
            acc[jj] += __builtin_amdgcn_logf(p); // v_log_f32 (log2)
        }
    }

    // Transpose through LDS for coalesced float4 stores.
    #pragma unroll
    for (int jj = 0; jj < JW; ++jj)
        s_acc[lane][jl0 + jj] = acc[jj];   // stride 17 -> conflict-free-ish
    __syncthreads();

    const int r = tid >> 2;        // b-row within tile
    const int c = tid & 3;         // float4 within 16-j row
    const float* sv = &s_acc[r][c * 4];
    float4 v;
    v.x = 1.0f / (1.0f - LN2 * sv[0]);
    v.y = 1.0f / (1.0f - LN2 * sv[1]);
    v.z = 1.0f / (1.0f - LN2 * sv[2]);
    v.w = 1.0f / (1.0f - LN2 * sv[3]);
    *(float4*)(out + (size_t)(b0 + r) * NOUT + j0 + c * 4) = v;
}

extern "C" void kernel_launch(void* const* d_in, const int* in_sizes, int n_in,
                              void* d_out, int out_size, void* d_ws, size_t ws_size,
                              hipStream_t stream) {
    const float* x = (const float*)d_in[0];   // (4096, 512) fp32
    const float* W = (const float*)d_in[1];   // (128, 512) fp32
    float* out = (float*)d_out;               // (4096, 128) fp32

    dim3 grid(BGROUPS * JGROUPS);             // 512 blocks
    dim3 block(256);
    hipLaunchKernelGGL(conj_kernel, grid, block, 0, stream, x, W, out);
}